// Round 1
// baseline (2475.386 us; speedup 1.0000x reference)
//
#include <hip/hip_runtime.h>
#include <cfloat>
#include <cstddef>

// ---------------------------------------------------------------------------
// SemanticRQVAE forward, fp32 baseline (round 0).
//   x[65536,384] -> enc1(relu) -> h1[.,512] -> enc2 -> z[.,512]
//   -> residual VQ (4 x 256 codes, dim 512) -> quantized, indices, commit_loss
//   -> dec1(relu) -> dec2 -> recon[.,384], recon_loss
// d_out layout (floats): recon (25165824) | indices as float (262144)
//                        | recon_loss | commit_loss
// ws layout (floats): bufA[33554432] | bufB[33554432] | cnorm[1024]
//                     | commitP[2048] | reconP[1536]
// ---------------------------------------------------------------------------

#define BATCH   65536
#define EDIM    384
#define HDIM    512
#define NCODE   256
#define NQ      4

#define OUT_IDX_OFF 25165824          // BATCH*EDIM
#define OUT_RL_OFF  25427968          // + BATCH*4
#define WS_BUFA     0
#define WS_BUFB     33554432          // BATCH*HDIM
#define WS_CNORM    67108864
#define WS_COMMITP  67109888
#define WS_RECONP   67111936

// ---------------------------------------------------------------------------
// Generic tiled f32 GEMM: C[M,N] = act(A[M,K] @ W[K,N] + bias)
// 128x128 tile, 256 threads, 8x8 micro-tile, BK=8.
// LOSS: also accumulate sum((C - X)^2) per block into lossP.
// ---------------------------------------------------------------------------
template <bool RELU, bool LOSS>
__global__ __launch_bounds__(256)
void gemm128(const float* __restrict__ A, const float* __restrict__ W,
             const float* __restrict__ bias, float* __restrict__ C,
             const float* __restrict__ X, float* __restrict__ lossP,
             int M, int N, int K)
{
    __shared__ float As[8][128];
    __shared__ float Bs[8][132];

    const int tid = threadIdx.x;
    const int tm = tid & 15;          // 0..15 (row group)
    const int tn = tid >> 4;          // 0..15 (col group)
    const int m0 = blockIdx.y * 128;
    const int n0 = blockIdx.x * 128;

    const int lm  = tid >> 1;         // A-load row 0..127
    const int lkq = (tid & 1) * 4;    // A-load k sub-offset
    const int lkb = tid >> 5;         // B-load k 0..7
    const int lnb = (tid & 31) * 4;   // B-load col 0..124

    float acc[8][8];
#pragma unroll
    for (int i = 0; i < 8; ++i)
#pragma unroll
        for (int j = 0; j < 8; ++j) acc[i][j] = 0.f;

    const float* Aptr = A + (size_t)(m0 + lm) * K + lkq;
    const float* Wptr = W + (size_t)lkb * N + n0 + lnb;

    for (int kt = 0; kt < K; kt += 8) {
        float4 a4 = *reinterpret_cast<const float4*>(Aptr + kt);
        float4 b4 = *reinterpret_cast<const float4*>(Wptr + (size_t)kt * N);
        __syncthreads();
        As[lkq + 0][lm] = a4.x;
        As[lkq + 1][lm] = a4.y;
        As[lkq + 2][lm] = a4.z;
        As[lkq + 3][lm] = a4.w;
        *reinterpret_cast<float4*>(&Bs[lkb][lnb]) = b4;
        __syncthreads();
#pragma unroll
        for (int k = 0; k < 8; ++k) {
            float4 al = *reinterpret_cast<const float4*>(&As[k][tm * 4]);
            float4 ah = *reinterpret_cast<const float4*>(&As[k][64 + tm * 4]);
            float4 bl = *reinterpret_cast<const float4*>(&Bs[k][tn * 4]);
            float4 bh = *reinterpret_cast<const float4*>(&Bs[k][64 + tn * 4]);
            float ar[8] = {al.x, al.y, al.z, al.w, ah.x, ah.y, ah.z, ah.w};
            float br[8] = {bl.x, bl.y, bl.z, bl.w, bh.x, bh.y, bh.z, bh.w};
#pragma unroll
            for (int i = 0; i < 8; ++i)
#pragma unroll
                for (int j = 0; j < 8; ++j)
                    acc[i][j] = fmaf(ar[i], br[j], acc[i][j]);
        }
    }

    // epilogue
    float4 bLo = *reinterpret_cast<const float4*>(bias + n0 + tn * 4);
    float4 bHi = *reinterpret_cast<const float4*>(bias + n0 + 64 + tn * 4);
    float bb[8] = {bLo.x, bLo.y, bLo.z, bLo.w, bHi.x, bHi.y, bHi.z, bHi.w};
    float lacc = 0.f;

#pragma unroll
    for (int i = 0; i < 8; ++i) {
        int r = (i < 4) ? (tm * 4 + i) : (64 + tm * 4 + i - 4);
        float* crow = C + (size_t)(m0 + r) * N + n0;
        float v[8];
#pragma unroll
        for (int j = 0; j < 8; ++j) {
            v[j] = acc[i][j] + bb[j];
            if (RELU) v[j] = v[j] > 0.f ? v[j] : 0.f;
        }
        float4 v0 = make_float4(v[0], v[1], v[2], v[3]);
        float4 v1 = make_float4(v[4], v[5], v[6], v[7]);
        *reinterpret_cast<float4*>(crow + tn * 4) = v0;
        *reinterpret_cast<float4*>(crow + 64 + tn * 4) = v1;
        if constexpr (LOSS) {
            const float* xrow = X + (size_t)(m0 + r) * N + n0;
            float4 x0 = *reinterpret_cast<const float4*>(xrow + tn * 4);
            float4 x1 = *reinterpret_cast<const float4*>(xrow + 64 + tn * 4);
            float xs[8] = {x0.x, x0.y, x0.z, x0.w, x1.x, x1.y, x1.z, x1.w};
#pragma unroll
            for (int j = 0; j < 8; ++j) {
                float d = v[j] - xs[j];
                lacc = fmaf(d, d, lacc);
            }
        }
    }

    if constexpr (LOSS) {
        __shared__ float red[256];
        red[tid] = lacc;
        __syncthreads();
        for (int s = 128; s > 0; s >>= 1) {
            if (tid < s) red[tid] += red[tid + s];
            __syncthreads();
        }
        if (tid == 0) lossP[blockIdx.y * gridDim.x + blockIdx.x] = red[0];
    }
}

// ---------------------------------------------------------------------------
// codebook squared norms: cnorm[q*256+c] = sum_k cb[q][c][k]^2
// one wave per code
// ---------------------------------------------------------------------------
__global__ __launch_bounds__(64)
void cnorm_kernel(const float* __restrict__ cb, float* __restrict__ cnorm)
{
    const int code = blockIdx.x;      // 0..1023
    const int lane = threadIdx.x;
    const float* r = cb + (size_t)code * HDIM;
    float s = 0.f;
    for (int k = lane; k < HDIM; k += 64) s = fmaf(r[k], r[k], s);
#pragma unroll
    for (int off = 32; off > 0; off >>= 1) s += __shfl_down(s, off);
    if (lane == 0) cnorm[code] = s;
}

// ---------------------------------------------------------------------------
// Fused residual VQ. 32 rows per block, residual lives in LDS (transposed).
// zq: in = z, out = quantized (in-place). idx_out: indices as float [B][4].
// ---------------------------------------------------------------------------
__global__ __launch_bounds__(256)
void vq_kernel(float* __restrict__ zq,
               const float* __restrict__ codebooks,   // [4*256*512]
               const float* __restrict__ cnorm,       // [1024]
               float* __restrict__ idx_out,
               float* __restrict__ commitP)
{
    __shared__ float res[512][32];        // 64 KB, res[k][row]
    __shared__ float cbu[8 * 260];        // union: cbs[8][260] / scval+scidx
    __shared__ int   idxrow[32];
    __shared__ float red[256];

    float (*cbs)[260] = reinterpret_cast<float (*)[260]>(cbu);
    float* scval = cbu;                                   // [32][32]
    int*   scidx = reinterpret_cast<int*>(cbu + 1024);    // [32][32]

    const int tid  = threadIdx.x;
    const int row0 = blockIdx.x * 32;

    // ---- stage z -> res (transposed), coalesced global reads ----
    {
        int row = tid >> 3, kseg = tid & 7;
        const float* zr = zq + (size_t)(row0 + row) * HDIM;
#pragma unroll
        for (int j = 0; j < 16; ++j) {
            int k = kseg * 4 + j * 32;
            float4 v = *reinterpret_cast<const float4*>(zr + k);
            res[k + 0][row] = v.x;
            res[k + 1][row] = v.y;
            res[k + 2][row] = v.z;
            res[k + 3][row] = v.w;
        }
    }
    // first barrier inside the q-loop orders these writes before reads

    const int rg = tid >> 5;   // 0..7  -> rows rg*4 .. rg*4+3
    const int cg = tid & 31;   // 0..31 -> codes cg*4..+3 and 128+cg*4..+3
    float commit_acc = 0.f;

    for (int q = 0; q < NQ; ++q) {
        const float* cbq = codebooks + (size_t)q * NCODE * HDIM;
        float acc[4][8];
#pragma unroll
        for (int i = 0; i < 4; ++i)
#pragma unroll
            for (int j = 0; j < 8; ++j) acc[i][j] = 0.f;

        for (int kt = 0; kt < HDIM; kt += 8) {
            const float* cr = cbq + (size_t)tid * HDIM + kt;
            float4 v0 = *reinterpret_cast<const float4*>(cr);
            float4 v1 = *reinterpret_cast<const float4*>(cr + 4);
            __syncthreads();                 // previous tile fully consumed
            cbs[0][tid] = v0.x; cbs[1][tid] = v0.y;
            cbs[2][tid] = v0.z; cbs[3][tid] = v0.w;
            cbs[4][tid] = v1.x; cbs[5][tid] = v1.y;
            cbs[6][tid] = v1.z; cbs[7][tid] = v1.w;
            __syncthreads();
#pragma unroll
            for (int k = 0; k < 8; ++k) {
                float4 rv = *reinterpret_cast<const float4*>(&res[kt + k][rg * 4]);
                float4 c0 = *reinterpret_cast<const float4*>(&cbs[k][cg * 4]);
                float4 c1 = *reinterpret_cast<const float4*>(&cbs[k][128 + cg * 4]);
                float a_[4] = {rv.x, rv.y, rv.z, rv.w};
                float b_[8] = {c0.x, c0.y, c0.z, c0.w, c1.x, c1.y, c1.z, c1.w};
#pragma unroll
                for (int i = 0; i < 4; ++i)
#pragma unroll
                    for (int j = 0; j < 8; ++j)
                        acc[i][j] = fmaf(a_[i], b_[j], acc[i][j]);
            }
        }

        // ---- scores + per-thread argmax (codes ascending within thread) ----
        float bv[4];
        int   bi[4];
#pragma unroll
        for (int i = 0; i < 4; ++i) { bv[i] = -FLT_MAX; bi[i] = 0; }
#pragma unroll
        for (int j = 0; j < 8; ++j) {
            int code = (j < 4) ? (cg * 4 + j) : (128 + cg * 4 + j - 4);
            float cn = cnorm[q * NCODE + code];
#pragma unroll
            for (int i = 0; i < 4; ++i) {
                float s = 2.f * acc[i][j] - cn;
                if (s > bv[i]) { bv[i] = s; bi[i] = code; }
            }
        }
        __syncthreads();                     // cbs dead -> reuse as scval/scidx
#pragma unroll
        for (int i = 0; i < 4; ++i) {
            scval[(rg * 4 + i) * 32 + cg] = bv[i];
            scidx[(rg * 4 + i) * 32 + cg] = bi[i];
        }
        __syncthreads();
        if (tid < 32) {
            float best = scval[tid * 32];
            int   bidx = scidx[tid * 32];
            for (int c2 = 1; c2 < 32; ++c2) {
                float v = scval[tid * 32 + c2];
                int  ix = scidx[tid * 32 + c2];
                if (v > best || (v == best && ix < bidx)) { best = v; bidx = ix; }
            }
            idxrow[tid] = bidx;
            idx_out[(size_t)(row0 + tid) * NQ + q] = (float)bidx;
        }
        __syncthreads();

        // ---- residual update + commit accumulation ----
        {
            int row = tid & 31, kq2 = tid >> 5;
            const float* crow = cbq + (size_t)idxrow[row] * HDIM;
#pragma unroll
            for (int j = 0; j < 16; ++j) {
                int k0 = j * 32 + kq2 * 4;
                float4 cv = *reinterpret_cast<const float4*>(crow + k0);
                float r0 = res[k0 + 0][row] - cv.x; res[k0 + 0][row] = r0;
                float r1 = res[k0 + 1][row] - cv.y; res[k0 + 1][row] = r1;
                float r2 = res[k0 + 2][row] - cv.z; res[k0 + 2][row] = r2;
                float r3 = res[k0 + 3][row] - cv.w; res[k0 + 3][row] = r3;
                commit_acc = fmaf(r0, r0, commit_acc);
                commit_acc = fmaf(r1, r1, commit_acc);
                commit_acc = fmaf(r2, r2, commit_acc);
                commit_acc = fmaf(r3, r3, commit_acc);
            }
        }
        // next q's first in-loop barrier orders res updates before reads
    }

    __syncthreads();                         // last updates done
    // ---- quantized = z - r_final, written in place over z ----
    {
        int row = tid >> 3, kseg = tid & 7;
        float* zr = zq + (size_t)(row0 + row) * HDIM;
#pragma unroll
        for (int j = 0; j < 16; ++j) {
            int k = kseg * 4 + j * 32;
            float4 v = *reinterpret_cast<const float4*>(zr + k);
            v.x -= res[k + 0][row];
            v.y -= res[k + 1][row];
            v.z -= res[k + 2][row];
            v.w -= res[k + 3][row];
            *reinterpret_cast<float4*>(zr + k) = v;
        }
    }

    // ---- commit partial reduce ----
    red[tid] = commit_acc;
    __syncthreads();
    for (int s = 128; s > 0; s >>= 1) {
        if (tid < s) red[tid] += red[tid + s];
        __syncthreads();
    }
    if (tid == 0) commitP[blockIdx.x] = red[0];
}

// ---------------------------------------------------------------------------
// deterministic final loss reduction
// ---------------------------------------------------------------------------
__global__ __launch_bounds__(256)
void loss_reduce(const float* __restrict__ cP, int nc,
                 const float* __restrict__ rP, int nr,
                 float* __restrict__ out2)
{
    __shared__ float red[256];
    const int tid = threadIdx.x;

    float s = 0.f;
    for (int i = tid; i < nc; i += 256) s += cP[i];
    red[tid] = s;
    __syncthreads();
    for (int st = 128; st > 0; st >>= 1) {
        if (tid < st) red[tid] += red[tid + st];
        __syncthreads();
    }
    float ctot = red[0];
    __syncthreads();

    s = 0.f;
    for (int i = tid; i < nr; i += 256) s += rP[i];
    red[tid] = s;
    __syncthreads();
    for (int st = 128; st > 0; st >>= 1) {
        if (tid < st) red[tid] += red[tid + st];
        __syncthreads();
    }
    if (tid == 0) {
        out2[0] = red[0] / ((float)BATCH * (float)EDIM);        // recon_loss
        out2[1] = 0.25f * ctot / ((float)BATCH * (float)HDIM);  // commit_loss
    }
}

// ---------------------------------------------------------------------------
extern "C" void kernel_launch(void* const* d_in, const int* in_sizes, int n_in,
                              void* d_out, int out_size, void* d_ws, size_t ws_size,
                              hipStream_t stream)
{
    const float* x   = (const float*)d_in[0];
    const float* ew1 = (const float*)d_in[1];
    const float* eb1 = (const float*)d_in[2];
    const float* ew2 = (const float*)d_in[3];
    const float* eb2 = (const float*)d_in[4];
    const float* cb  = (const float*)d_in[5];
    const float* dw1 = (const float*)d_in[6];
    const float* db1 = (const float*)d_in[7];
    const float* dw2 = (const float*)d_in[8];
    const float* db2 = (const float*)d_in[9];

    float* out  = (float*)d_out;
    float* ws   = (float*)d_ws;
    float* bufA = ws + WS_BUFA;     // h1, later dec hidden
    float* bufB = ws + WS_BUFB;     // z, becomes quantized in-place
    float* cn   = ws + WS_CNORM;
    float* cP   = ws + WS_COMMITP;  // 2048 commit partials
    float* rP   = ws + WS_RECONP;   // 1536 recon partials

    // codebook norms
    cnorm_kernel<<<NQ * NCODE, 64, 0, stream>>>(cb, cn);

    // encoder
    gemm128<true, false><<<dim3(HDIM / 128, BATCH / 128), 256, 0, stream>>>(
        x, ew1, eb1, bufA, nullptr, nullptr, BATCH, HDIM, EDIM);
    gemm128<false, false><<<dim3(HDIM / 128, BATCH / 128), 256, 0, stream>>>(
        bufA, ew2, eb2, bufB, nullptr, nullptr, BATCH, HDIM, HDIM);

    // residual VQ (z -> quantized in place, indices, commit partials)
    vq_kernel<<<BATCH / 32, 256, 0, stream>>>(
        bufB, cb, cn, out + OUT_IDX_OFF, cP);

    // decoder
    gemm128<true, false><<<dim3(HDIM / 128, BATCH / 128), 256, 0, stream>>>(
        bufB, dw1, db1, bufA, nullptr, nullptr, BATCH, HDIM, HDIM);
    gemm128<false, true><<<dim3(EDIM / 128, BATCH / 128), 256, 0, stream>>>(
        bufA, dw2, db2, out, x, rP, BATCH, EDIM, HDIM);

    // losses
    loss_reduce<<<1, 256, 0, stream>>>(cP, BATCH / 32, rP,
                                       (BATCH / 128) * (EDIM / 128),
                                       out + OUT_RL_OFF);
}

// Round 2
// 1826.139 us; speedup vs baseline: 1.3555x; 1.3555x over previous
//
#include <hip/hip_runtime.h>
#include <cfloat>
#include <cstddef>

// ---------------------------------------------------------------------------
// SemanticRQVAE forward, round 1: f32 GEMMs + MFMA (f16 split-2) residual VQ.
// d_out layout (floats): recon (25165824) | indices as float (262144)
//                        | recon_loss | commit_loss
// ws layout (floats): bufA[33554432] | bufB[33554432] | cbsplit[524288 f32 =
//                     1,048,576 u16] | cnorm[1024] | commitP[2048] | reconP[1536]
// ---------------------------------------------------------------------------

#define BATCH   65536
#define EDIM    384
#define HDIM    512
#define NCODE   256
#define NQ      4

#define OUT_IDX_OFF 25165824          // BATCH*EDIM
#define OUT_RL_OFF  25427968          // + BATCH*4
#define WS_BUFA     0
#define WS_BUFB     33554432
#define WS_CBSPL    67108864          // 524288 floats (2 MB of u16 f16 data)
#define WS_CNORM    67633152
#define WS_COMMITP  67634176          // 4*512
#define WS_RECONP   67636224

typedef _Float16 half8 __attribute__((ext_vector_type(8)));
typedef float    f32x16 __attribute__((ext_vector_type(16)));
typedef short    short8 __attribute__((ext_vector_type(8)));

// ---------------------------------------------------------------------------
// Generic tiled f32 GEMM (unchanged from round 0, correctness-proven).
// ---------------------------------------------------------------------------
template <bool RELU, bool LOSS>
__global__ __launch_bounds__(256)
void gemm128(const float* __restrict__ A, const float* __restrict__ W,
             const float* __restrict__ bias, float* __restrict__ C,
             const float* __restrict__ X, float* __restrict__ lossP,
             int M, int N, int K)
{
    __shared__ float As[8][128];
    __shared__ float Bs[8][132];

    const int tid = threadIdx.x;
    const int tm = tid & 15;
    const int tn = tid >> 4;
    const int m0 = blockIdx.y * 128;
    const int n0 = blockIdx.x * 128;

    const int lm  = tid >> 1;
    const int lkq = (tid & 1) * 4;
    const int lkb = tid >> 5;
    const int lnb = (tid & 31) * 4;

    float acc[8][8];
#pragma unroll
    for (int i = 0; i < 8; ++i)
#pragma unroll
        for (int j = 0; j < 8; ++j) acc[i][j] = 0.f;

    const float* Aptr = A + (size_t)(m0 + lm) * K + lkq;
    const float* Wptr = W + (size_t)lkb * N + n0 + lnb;

    for (int kt = 0; kt < K; kt += 8) {
        float4 a4 = *reinterpret_cast<const float4*>(Aptr + kt);
        float4 b4 = *reinterpret_cast<const float4*>(Wptr + (size_t)kt * N);
        __syncthreads();
        As[lkq + 0][lm] = a4.x;
        As[lkq + 1][lm] = a4.y;
        As[lkq + 2][lm] = a4.z;
        As[lkq + 3][lm] = a4.w;
        *reinterpret_cast<float4*>(&Bs[lkb][lnb]) = b4;
        __syncthreads();
#pragma unroll
        for (int k = 0; k < 8; ++k) {
            float4 al = *reinterpret_cast<const float4*>(&As[k][tm * 4]);
            float4 ah = *reinterpret_cast<const float4*>(&As[k][64 + tm * 4]);
            float4 bl = *reinterpret_cast<const float4*>(&Bs[k][tn * 4]);
            float4 bh = *reinterpret_cast<const float4*>(&Bs[k][64 + tn * 4]);
            float ar[8] = {al.x, al.y, al.z, al.w, ah.x, ah.y, ah.z, ah.w};
            float br[8] = {bl.x, bl.y, bl.z, bl.w, bh.x, bh.y, bh.z, bh.w};
#pragma unroll
            for (int i = 0; i < 8; ++i)
#pragma unroll
                for (int j = 0; j < 8; ++j)
                    acc[i][j] = fmaf(ar[i], br[j], acc[i][j]);
        }
    }

    float4 bLo = *reinterpret_cast<const float4*>(bias + n0 + tn * 4);
    float4 bHi = *reinterpret_cast<const float4*>(bias + n0 + 64 + tn * 4);
    float bb[8] = {bLo.x, bLo.y, bLo.z, bLo.w, bHi.x, bHi.y, bHi.z, bHi.w};
    float lacc = 0.f;

#pragma unroll
    for (int i = 0; i < 8; ++i) {
        int r = (i < 4) ? (tm * 4 + i) : (64 + tm * 4 + i - 4);
        float* crow = C + (size_t)(m0 + r) * N + n0;
        float v[8];
#pragma unroll
        for (int j = 0; j < 8; ++j) {
            v[j] = acc[i][j] + bb[j];
            if (RELU) v[j] = v[j] > 0.f ? v[j] : 0.f;
        }
        float4 v0 = make_float4(v[0], v[1], v[2], v[3]);
        float4 v1 = make_float4(v[4], v[5], v[6], v[7]);
        *reinterpret_cast<float4*>(crow + tn * 4) = v0;
        *reinterpret_cast<float4*>(crow + 64 + tn * 4) = v1;
        if constexpr (LOSS) {
            const float* xrow = X + (size_t)(m0 + r) * N + n0;
            float4 x0 = *reinterpret_cast<const float4*>(xrow + tn * 4);
            float4 x1 = *reinterpret_cast<const float4*>(xrow + 64 + tn * 4);
            float xs[8] = {x0.x, x0.y, x0.z, x0.w, x1.x, x1.y, x1.z, x1.w};
#pragma unroll
            for (int j = 0; j < 8; ++j) {
                float d = v[j] - xs[j];
                lacc = fmaf(d, d, lacc);
            }
        }
    }

    if constexpr (LOSS) {
        __shared__ float red[256];
        red[tid] = lacc;
        __syncthreads();
        for (int s = 128; s > 0; s >>= 1) {
            if (tid < s) red[tid] += red[tid + s];
            __syncthreads();
        }
        if (tid == 0) lossP[blockIdx.y * gridDim.x + blockIdx.x] = red[0];
    }
}

// ---------------------------------------------------------------------------
// codebook squared norms (exact f32)
// ---------------------------------------------------------------------------
__global__ __launch_bounds__(64)
void cnorm_kernel(const float* __restrict__ cb, float* __restrict__ cnorm)
{
    const int code = blockIdx.x;      // 0..1023
    const int lane = threadIdx.x;
    const float* r = cb + (size_t)code * HDIM;
    float s = 0.f;
    for (int k = lane; k < HDIM; k += 64) s = fmaf(r[k], r[k], s);
#pragma unroll
    for (int off = 32; off > 0; off >>= 1) s += __shfl_down(s, off);
    if (lane == 0) cnorm[code] = s;
}

// ---------------------------------------------------------------------------
// Split f32 codebook into f16 hi/lo, stored tile-ready for the VQ kernel:
// u16 layout: [q][kt=32][half h/l][khalf][code 256][j 8]
//   h at off, l at off + 4096 (u16 units within the 8192-u16 kt-image)
// ---------------------------------------------------------------------------
__global__ __launch_bounds__(256)
void split_cb(const float* __restrict__ cb, unsigned short* __restrict__ out)
{
    int u = blockIdx.x * 256 + threadIdx.x;    // 65536 units = [q][code][kt][khalf]
    int q    = u >> 14;
    int rem  = u & 16383;
    int code = rem >> 6;
    int kt   = (rem >> 1) & 31;
    int khalf = rem & 1;
    int k = kt * 16 + khalf * 8;
    const float* p = cb + ((size_t)(q * NCODE + code)) * HDIM + k;
    float4 v0 = *reinterpret_cast<const float4*>(p);
    float4 v1 = *reinterpret_cast<const float4*>(p + 4);
    float vs[8] = {v0.x, v0.y, v0.z, v0.w, v1.x, v1.y, v1.z, v1.w};
    half8 h, l;
#pragma unroll
    for (int j = 0; j < 8; ++j) {
        _Float16 hv = (_Float16)vs[j];
        h[j] = hv;
        l[j] = (_Float16)(vs[j] - (float)hv);
    }
    size_t o = (size_t)(q * 32 + kt) * 8192 + (size_t)khalf * 2048 + (size_t)code * 8;
    *reinterpret_cast<half8*>(out + o)        = h;
    *reinterpret_cast<half8*>(out + o + 4096) = l;
}

// ---------------------------------------------------------------------------
// One residual-VQ stage.
// Block: 128 rows x 256 codes, 4 waves in a 2x2 (M x N) grid.
// GEMM: S = R @ CB^T via f16 split-2 mfma_f32_32x32x16_f16 (3 mfma / k-tile).
// Then: argmax per row (first-max), residual update in place, commit partial.
// LAST stage: writes quant = z - R' into zq (in place over z).
// ---------------------------------------------------------------------------
template <bool LAST>
__global__ __launch_bounds__(256, 2)
void vq_stage(int q,
              const float* Rin,             // residual source
              float* Rout,                  // residual dest (in place; LAST: = zq)
              const float* zsrc,            // LAST only: z
              const unsigned short* __restrict__ cbs,
              const float* __restrict__ cb, // f32 codebook
              const float* __restrict__ cnorm,
              float* __restrict__ idx_out,
              float* __restrict__ commitP)
{
    __shared__ __align__(16) _Float16 Ab[2][2][2][128][8]; // [db][h/l][khalf][row][j] 16KB
    __shared__ __align__(16) _Float16 Bb[2][2][2][256][8]; // [db][h/l][khalf][code][j] 32KB
    __shared__ float sval[2][128];
    __shared__ int   sidx[2][128];
    __shared__ int   idxbuf[128];
    __shared__ float red[256];

    const int tid  = threadIdx.x;
    const int wid  = tid >> 6;
    const int lane = tid & 63;
    const int l31  = lane & 31;
    const int lh   = lane >> 5;          // khalf selector
    const int wm   = wid >> 1;           // 0..1: row half (64 rows)
    const int wn   = wid & 1;            // 0..1: code half (128 codes)
    const int row0 = blockIdx.x * 128;

    f32x16 acc[2][4];
#pragma unroll
    for (int m = 0; m < 2; ++m)
#pragma unroll
        for (int n = 0; n < 4; ++n) acc[m][n] = (f32x16)(0.0f);

    const int arow = tid >> 1;           // A-stage row
    const int akh  = tid & 1;            // A-stage khalf

    // ---- staging helpers ----
    auto stageB = [&](int db, int kt) {
        const short8* src = reinterpret_cast<const short8*>(cbs + (size_t)(q * 32 + kt) * 8192);
        short8* dst = reinterpret_cast<short8*>(&Bb[db][0][0][0][0]);
#pragma unroll
        for (int i = 0; i < 4; ++i)
            dst[i * 256 + tid] = src[i * 256 + tid];
    };
    auto loadA = [&](int kt, float4& a0, float4& a1) {
        const float* p = Rin + (size_t)(row0 + arow) * HDIM + kt * 16 + akh * 8;
        a0 = *reinterpret_cast<const float4*>(p);
        a1 = *reinterpret_cast<const float4*>(p + 4);
    };
    auto writeA = [&](int db, float4 a0, float4 a1) {
        float vs[8] = {a0.x, a0.y, a0.z, a0.w, a1.x, a1.y, a1.z, a1.w};
        half8 h, l;
#pragma unroll
        for (int j = 0; j < 8; ++j) {
            _Float16 hv = (_Float16)vs[j];
            h[j] = hv;
            l[j] = (_Float16)(vs[j] - (float)hv);
        }
        *reinterpret_cast<half8*>(&Ab[db][0][akh][arow][0]) = h;
        *reinterpret_cast<half8*>(&Ab[db][1][akh][arow][0]) = l;
    };

    // ---- prologue: stage kt=0 -> buf0, kt=1 -> buf1 ----
    {
        float4 ra0, ra1;
        loadA(0, ra0, ra1);
        stageB(0, 0);
        writeA(0, ra0, ra1);
        loadA(1, ra0, ra1);
        stageB(1, 1);
        writeA(1, ra0, ra1);
    }

    // ---- main K loop: 32 tiles of 16 ----
    float4 pa0, pa1;
    for (int kt = 0; kt < 32; ++kt) {
        const int db = kt & 1;
        __syncthreads();                          // staged data for kt visible
        if (kt + 2 < 32) loadA(kt + 2, pa0, pa1); // issue global loads early

        const int rb = wm * 64 + l31;
        half8 Ah0 = *reinterpret_cast<const half8*>(&Ab[db][0][lh][rb][0]);
        half8 Al0 = *reinterpret_cast<const half8*>(&Ab[db][1][lh][rb][0]);
        half8 Ah1 = *reinterpret_cast<const half8*>(&Ab[db][0][lh][rb + 32][0]);
        half8 Al1 = *reinterpret_cast<const half8*>(&Ab[db][1][lh][rb + 32][0]);
#pragma unroll
        for (int nt = 0; nt < 4; ++nt) {
            const int code = wn * 128 + nt * 32 + l31;
            half8 Bh = *reinterpret_cast<const half8*>(&Bb[db][0][lh][code][0]);
            half8 Bl = *reinterpret_cast<const half8*>(&Bb[db][1][lh][code][0]);
            acc[0][nt] = __builtin_amdgcn_mfma_f32_32x32x16_f16(Ah0, Bh, acc[0][nt], 0, 0, 0);
            acc[0][nt] = __builtin_amdgcn_mfma_f32_32x32x16_f16(Ah0, Bl, acc[0][nt], 0, 0, 0);
            acc[0][nt] = __builtin_amdgcn_mfma_f32_32x32x16_f16(Al0, Bh, acc[0][nt], 0, 0, 0);
            acc[1][nt] = __builtin_amdgcn_mfma_f32_32x32x16_f16(Ah1, Bh, acc[1][nt], 0, 0, 0);
            acc[1][nt] = __builtin_amdgcn_mfma_f32_32x32x16_f16(Ah1, Bl, acc[1][nt], 0, 0, 0);
            acc[1][nt] = __builtin_amdgcn_mfma_f32_32x32x16_f16(Al1, Bh, acc[1][nt], 0, 0, 0);
        }
        __syncthreads();                          // readers done with buf db
        if (kt + 2 < 32) { stageB(db, kt + 2); writeA(db, pa0, pa1); }
    }

    // ---- scores + per-row argmax ----
    const float* cn = cnorm + q * NCODE;
#pragma unroll
    for (int Mt = 0; Mt < 2; ++Mt) {
#pragma unroll
        for (int rg = 0; rg < 16; ++rg) {
            float bv = -FLT_MAX;
            int   bi = 0;
#pragma unroll
            for (int nt = 0; nt < 4; ++nt) {
                const int code = wn * 128 + nt * 32 + l31;
                float s = 2.f * acc[Mt][nt][rg] - cn[code];
                if (s > bv || (s == bv && code < bi)) { bv = s; bi = code; }
            }
#pragma unroll
            for (int m = 1; m < 32; m <<= 1) {
                float ov = __shfl_xor(bv, m, 64);
                int   oi = __shfl_xor(bi, m, 64);
                if (ov > bv || (ov == bv && oi < bi)) { bv = ov; bi = oi; }
            }
            if (l31 == 0) {
                int row = wm * 64 + Mt * 32 + (rg & 3) + 8 * (rg >> 2) + 4 * lh;
                sval[wn][row] = bv;
                sidx[wn][row] = bi;
            }
        }
    }
    __syncthreads();
    if (tid < 128) {
        float v0 = sval[0][tid], v1 = sval[1][tid];
        int   i0 = sidx[0][tid], i1 = sidx[1][tid];
        int b = (v1 > v0 || (v1 == v0 && i1 < i0)) ? i1 : i0;
        idxbuf[tid] = b;
        idx_out[(size_t)(row0 + tid) * NQ + q] = (float)b;
    }
    __syncthreads();

    // ---- residual update (+ commit partial; LAST: quant = z - R') ----
    float ca = 0.f;
    const int rgrp = tid >> 3;   // 0..31
    const int lpos = tid & 7;    // 0..7
#pragma unroll
    for (int rr = 0; rr < 4; ++rr) {
        const int row = rr * 32 + rgrp;
        const float* rin  = Rin + (size_t)(row0 + row) * HDIM;
        const float* crow = cb + ((size_t)q * NCODE + idxbuf[row]) * HDIM;
        float* rout = Rout + (size_t)(row0 + row) * HDIM;
        const float* zr = LAST ? (zsrc + (size_t)(row0 + row) * HDIM) : nullptr;
#pragma unroll
        for (int j = 0; j < 16; ++j) {
            const int f4 = lpos + j * 8;
            float4 rv = *reinterpret_cast<const float4*>(rin + f4 * 4);
            float4 cv = *reinterpret_cast<const float4*>(crow + f4 * 4);
            float4 d;
            d.x = rv.x - cv.x; d.y = rv.y - cv.y;
            d.z = rv.z - cv.z; d.w = rv.w - cv.w;
            ca = fmaf(d.x, d.x, ca); ca = fmaf(d.y, d.y, ca);
            ca = fmaf(d.z, d.z, ca); ca = fmaf(d.w, d.w, ca);
            if constexpr (LAST) {
                float4 zv = *reinterpret_cast<const float4*>(zr + f4 * 4);
                float4 qv;
                qv.x = zv.x - d.x; qv.y = zv.y - d.y;
                qv.z = zv.z - d.z; qv.w = zv.w - d.w;
                *reinterpret_cast<float4*>(rout + f4 * 4) = qv;
            } else {
                *reinterpret_cast<float4*>(rout + f4 * 4) = d;
            }
        }
    }

    red[tid] = ca;
    __syncthreads();
    for (int s = 128; s > 0; s >>= 1) {
        if (tid < s) red[tid] += red[tid + s];
        __syncthreads();
    }
    if (tid == 0) commitP[q * 512 + blockIdx.x] = red[0];
}

// ---------------------------------------------------------------------------
// deterministic final loss reduction
// ---------------------------------------------------------------------------
__global__ __launch_bounds__(256)
void loss_reduce(const float* __restrict__ cP, int nc,
                 const float* __restrict__ rP, int nr,
                 float* __restrict__ out2)
{
    __shared__ float red[256];
    const int tid = threadIdx.x;

    float s = 0.f;
    for (int i = tid; i < nc; i += 256) s += cP[i];
    red[tid] = s;
    __syncthreads();
    for (int st = 128; st > 0; st >>= 1) {
        if (tid < st) red[tid] += red[tid + st];
        __syncthreads();
    }
    float ctot = red[0];
    __syncthreads();

    s = 0.f;
    for (int i = tid; i < nr; i += 256) s += rP[i];
    red[tid] = s;
    __syncthreads();
    for (int st = 128; st > 0; st >>= 1) {
        if (tid < st) red[tid] += red[tid + st];
        __syncthreads();
    }
    if (tid == 0) {
        out2[0] = red[0] / ((float)BATCH * (float)EDIM);
        out2[1] = 0.25f * ctot / ((float)BATCH * (float)HDIM);
    }
}

// ---------------------------------------------------------------------------
extern "C" void kernel_launch(void* const* d_in, const int* in_sizes, int n_in,
                              void* d_out, int out_size, void* d_ws, size_t ws_size,
                              hipStream_t stream)
{
    const float* x   = (const float*)d_in[0];
    const float* ew1 = (const float*)d_in[1];
    const float* eb1 = (const float*)d_in[2];
    const float* ew2 = (const float*)d_in[3];
    const float* eb2 = (const float*)d_in[4];
    const float* cb  = (const float*)d_in[5];
    const float* dw1 = (const float*)d_in[6];
    const float* db1 = (const float*)d_in[7];
    const float* dw2 = (const float*)d_in[8];
    const float* db2 = (const float*)d_in[9];

    float* out  = (float*)d_out;
    float* ws   = (float*)d_ws;
    float* bufA = ws + WS_BUFA;                       // h1 -> residual -> dec hidden
    float* bufB = ws + WS_BUFB;                       // z -> quantized (in place)
    unsigned short* cbs = (unsigned short*)(ws + WS_CBSPL);
    float* cn   = ws + WS_CNORM;
    float* cP   = ws + WS_COMMITP;                    // [4][512]
    float* rP   = ws + WS_RECONP;

    // codebook prep
    cnorm_kernel<<<NQ * NCODE, 64, 0, stream>>>(cb, cn);
    split_cb<<<256, 256, 0, stream>>>(cb, cbs);

    // encoder (f32)
    gemm128<true, false><<<dim3(HDIM / 128, BATCH / 128), 256, 0, stream>>>(
        x, ew1, eb1, bufA, nullptr, nullptr, BATCH, HDIM, EDIM);
    gemm128<false, false><<<dim3(HDIM / 128, BATCH / 128), 256, 0, stream>>>(
        bufA, ew2, eb2, bufB, nullptr, nullptr, BATCH, HDIM, HDIM);

    // residual VQ: 4 MFMA stages
    float* idxo = out + OUT_IDX_OFF;
    vq_stage<false><<<512, 256, 0, stream>>>(0, bufB, bufA, nullptr, cbs, cb, cn, idxo, cP);
    vq_stage<false><<<512, 256, 0, stream>>>(1, bufA, bufA, nullptr, cbs, cb, cn, idxo, cP);
    vq_stage<false><<<512, 256, 0, stream>>>(2, bufA, bufA, nullptr, cbs, cb, cn, idxo, cP);
    vq_stage<true ><<<512, 256, 0, stream>>>(3, bufA, bufB, bufB,    cbs, cb, cn, idxo, cP);

    // decoder (f32)
    gemm128<true, false><<<dim3(HDIM / 128, BATCH / 128), 256, 0, stream>>>(
        bufB, dw1, db1, bufA, nullptr, nullptr, BATCH, HDIM, HDIM);
    gemm128<false, true><<<dim3(EDIM / 128, BATCH / 128), 256, 0, stream>>>(
        bufA, dw2, db2, out, x, rP, BATCH, EDIM, HDIM);

    // losses
    loss_reduce<<<1, 256, 0, stream>>>(cP, NQ * 512, rP,
                                       (BATCH / 128) * (EDIM / 128),
                                       out + OUT_RL_OFF);
}

// Round 3
// 972.880 us; speedup vs baseline: 2.5444x; 1.8770x over previous
//
#include <hip/hip_runtime.h>
#include <cfloat>
#include <cstddef>

// ---------------------------------------------------------------------------
// SemanticRQVAE forward, round 2: all GEMMs + VQ on MFMA (f16 split-2).
// d_out layout (floats): recon (25165824) | indices as float (262144)
//                        | recon_loss | commit_loss
// ws layout (floats):
//   bufA[33554432] | bufB[33554432] | cbsplit[524288] | cnorm[1024]
//   | commitP[2048] | reconP[1536] | w1s[196608] | w2s[262144]
//   | w3s[262144] | w4s[196608]
// ---------------------------------------------------------------------------

#define BATCH   65536
#define EDIM    384
#define HDIM    512
#define NCODE   256
#define NQ      4

#define OUT_IDX_OFF 25165824          // BATCH*EDIM
#define OUT_RL_OFF  25427968          // + BATCH*4
#define WS_BUFA     0
#define WS_BUFB     33554432
#define WS_CBSPL    67108864
#define WS_CNORM    67633152
#define WS_COMMITP  67634176
#define WS_RECONP   67636224
#define WS_W1S      67637760          // 384*512 floats
#define WS_W2S      67834368          // 512*512
#define WS_W3S      68096512          // 512*512
#define WS_W4S      68358656          // 512*384  (ends 68555264)

typedef _Float16 half8 __attribute__((ext_vector_type(8)));
typedef float    f32x16 __attribute__((ext_vector_type(16)));
typedef short    short8 __attribute__((ext_vector_type(8)));

// ---------------------------------------------------------------------------
// Split f32 weight W[K][N] into f16 hi/lo, tile-ready u16 layout:
//   entry(kt, hl, khalf, col) = ((kt*2 + hl)*2 + khalf)*N + col, 8 u16 each
//   holding k = kt*16 + khalf*8 + j, j=0..7.
// One thread per (kt, khalf, col) unit. Launch units = (K/16)*2*N threads.
// ---------------------------------------------------------------------------
__global__ __launch_bounds__(256)
void split_w(const float* __restrict__ W, unsigned short* __restrict__ out,
             int N, int K)
{
    int u = blockIdx.x * 256 + threadIdx.x;
    int col  = u % N;
    int rem  = u / N;
    int khalf = rem & 1;
    int kt    = rem >> 1;
    int kbase = kt * 16 + khalf * 8;
    half8 h, l;
#pragma unroll
    for (int j = 0; j < 8; ++j) {
        float v = W[(size_t)(kbase + j) * N + col];
        _Float16 hv = (_Float16)v;
        h[j] = hv;
        l[j] = (_Float16)(v - (float)hv);
    }
    size_t eh = ((size_t)(kt * 4 + khalf)) * N + col;        // hl=0
    size_t el = ((size_t)(kt * 4 + 2 + khalf)) * N + col;    // hl=1
    *reinterpret_cast<half8*>(out + eh * 8) = h;
    *reinterpret_cast<half8*>(out + el * 8) = l;
}

// ---------------------------------------------------------------------------
// MFMA GEMM: C[M,N] = act(A[M,K] @ W[K,N] + bias), f16 split-2 (3 mfma/tile).
// Block: 128 rows x BN cols, 4 waves. BN=256 -> waves 2x2 (64x128 each);
// BN=128 -> waves 4x1 (32x128 each). K-tiles of 16, double-buffered.
// LOSS: accumulate sum((C - X)^2) per block into lossP.
// ---------------------------------------------------------------------------
template <int BN, bool RELU, bool LOSS>
__global__ __launch_bounds__(256, 2)
void gemm_mfma(const float* __restrict__ A, const unsigned short* __restrict__ Wsp,
               const float* __restrict__ bias, float* __restrict__ C,
               const float* __restrict__ X, float* __restrict__ lossP,
               int N, int K)
{
    constexpr int WN = BN / 128;          // waves along N
    constexpr int WM = 4 / WN;            // waves along M
    constexpr int MR = 128 / WM;          // rows per wave
    constexpr int FM = MR / 32;           // 32-row frags per wave
    constexpr int LOG_BN = (BN == 256) ? 8 : 7;

    __shared__ __align__(16) _Float16 Ab[2][2][2][128][8]; // [db][hl][khalf][row][j]
    __shared__ __align__(16) _Float16 Bb[2][2][2][BN][8];  // [db][hl][khalf][col][j]
    __shared__ float red[256];

    const int tid  = threadIdx.x;
    const int wid  = tid >> 6;
    const int lane = tid & 63;
    const int l31  = lane & 31;
    const int lh   = lane >> 5;
    const int wm   = wid / WN;
    const int wn   = wid % WN;
    const int row0 = blockIdx.y * 128;
    const int n0   = blockIdx.x * BN;
    const int nkt  = K / 16;

    f32x16 acc[FM][4];
#pragma unroll
    for (int m = 0; m < FM; ++m)
#pragma unroll
        for (int n = 0; n < 4; ++n) acc[m][n] = (f32x16)(0.0f);

    const int arow = tid >> 1;
    const int akh  = tid & 1;

    auto stageB = [&](int db, int kt) {
        const short8* src = reinterpret_cast<const short8*>(Wsp) + (size_t)kt * 4 * N;
        short8* dst = reinterpret_cast<short8*>(&Bb[db][0][0][0][0]);
#pragma unroll
        for (int i = 0; i < BN / 64; ++i) {
            int e    = i * 256 + tid;
            int hlkh = e >> LOG_BN;
            int col  = e & (BN - 1);
            dst[e] = src[(size_t)hlkh * N + n0 + col];
        }
    };
    auto loadA = [&](int kt, float4& a0, float4& a1) {
        const float* p = A + (size_t)(row0 + arow) * K + kt * 16 + akh * 8;
        a0 = *reinterpret_cast<const float4*>(p);
        a1 = *reinterpret_cast<const float4*>(p + 4);
    };
    auto writeA = [&](int db, float4 a0, float4 a1) {
        float vs[8] = {a0.x, a0.y, a0.z, a0.w, a1.x, a1.y, a1.z, a1.w};
        half8 h, l;
#pragma unroll
        for (int j = 0; j < 8; ++j) {
            _Float16 hv = (_Float16)vs[j];
            h[j] = hv;
            l[j] = (_Float16)(vs[j] - (float)hv);
        }
        *reinterpret_cast<half8*>(&Ab[db][0][akh][arow][0]) = h;
        *reinterpret_cast<half8*>(&Ab[db][1][akh][arow][0]) = l;
    };

    // prologue: stage kt=0 -> buf0, kt=1 -> buf1
    {
        float4 ra0, ra1;
        loadA(0, ra0, ra1);
        stageB(0, 0);
        writeA(0, ra0, ra1);
        loadA(1, ra0, ra1);
        stageB(1, 1);
        writeA(1, ra0, ra1);
    }

    float4 pa0, pa1;
    for (int kt = 0; kt < nkt; ++kt) {
        const int db = kt & 1;
        __syncthreads();
        if (kt + 2 < nkt) loadA(kt + 2, pa0, pa1);

        half8 Ah[FM], Al[FM];
#pragma unroll
        for (int fm = 0; fm < FM; ++fm) {
            const int rb = wm * MR + fm * 32 + l31;
            Ah[fm] = *reinterpret_cast<const half8*>(&Ab[db][0][lh][rb][0]);
            Al[fm] = *reinterpret_cast<const half8*>(&Ab[db][1][lh][rb][0]);
        }
#pragma unroll
        for (int nt = 0; nt < 4; ++nt) {
            const int col = wn * 128 + nt * 32 + l31;
            half8 Bh = *reinterpret_cast<const half8*>(&Bb[db][0][lh][col][0]);
            half8 Bl = *reinterpret_cast<const half8*>(&Bb[db][1][lh][col][0]);
#pragma unroll
            for (int fm = 0; fm < FM; ++fm) {
                acc[fm][nt] = __builtin_amdgcn_mfma_f32_32x32x16_f16(Ah[fm], Bh, acc[fm][nt], 0, 0, 0);
                acc[fm][nt] = __builtin_amdgcn_mfma_f32_32x32x16_f16(Ah[fm], Bl, acc[fm][nt], 0, 0, 0);
                acc[fm][nt] = __builtin_amdgcn_mfma_f32_32x32x16_f16(Al[fm], Bh, acc[fm][nt], 0, 0, 0);
            }
        }
        __syncthreads();
        if (kt + 2 < nkt) { stageB(db, kt + 2); writeA(db, pa0, pa1); }
    }

    // epilogue: bias (+relu) (+loss) + scattered-but-row-coalesced stores
    float lacc = 0.f;
#pragma unroll
    for (int fm = 0; fm < FM; ++fm) {
#pragma unroll
        for (int nt = 0; nt < 4; ++nt) {
            const int col = n0 + wn * 128 + nt * 32 + l31;
            const float b = bias[col];
#pragma unroll
            for (int rg = 0; rg < 16; ++rg) {
                const int row = row0 + wm * MR + fm * 32 + (rg & 3) + 8 * (rg >> 2) + 4 * lh;
                float v = acc[fm][nt][rg] + b;
                if (RELU) v = v > 0.f ? v : 0.f;
                C[(size_t)row * N + col] = v;
                if constexpr (LOSS) {
                    float d = v - X[(size_t)row * N + col];
                    lacc = fmaf(d, d, lacc);
                }
            }
        }
    }

    if constexpr (LOSS) {
        red[tid] = lacc;
        __syncthreads();
        for (int s = 128; s > 0; s >>= 1) {
            if (tid < s) red[tid] += red[tid + s];
            __syncthreads();
        }
        if (tid == 0) lossP[blockIdx.y * gridDim.x + blockIdx.x] = red[0];
    }
}

// ---------------------------------------------------------------------------
// codebook squared norms (exact f32)
// ---------------------------------------------------------------------------
__global__ __launch_bounds__(64)
void cnorm_kernel(const float* __restrict__ cb, float* __restrict__ cnorm)
{
    const int code = blockIdx.x;
    const int lane = threadIdx.x;
    const float* r = cb + (size_t)code * HDIM;
    float s = 0.f;
    for (int k = lane; k < HDIM; k += 64) s = fmaf(r[k], r[k], s);
#pragma unroll
    for (int off = 32; off > 0; off >>= 1) s += __shfl_down(s, off);
    if (lane == 0) cnorm[code] = s;
}

// ---------------------------------------------------------------------------
// Split f32 codebook into f16 hi/lo tile-ready layout (as round 1).
// ---------------------------------------------------------------------------
__global__ __launch_bounds__(256)
void split_cb(const float* __restrict__ cb, unsigned short* __restrict__ out)
{
    int u = blockIdx.x * 256 + threadIdx.x;
    int q    = u >> 14;
    int rem  = u & 16383;
    int code = rem >> 6;
    int kt   = (rem >> 1) & 31;
    int khalf = rem & 1;
    int k = kt * 16 + khalf * 8;
    const float* p = cb + ((size_t)(q * NCODE + code)) * HDIM + k;
    float4 v0 = *reinterpret_cast<const float4*>(p);
    float4 v1 = *reinterpret_cast<const float4*>(p + 4);
    float vs[8] = {v0.x, v0.y, v0.z, v0.w, v1.x, v1.y, v1.z, v1.w};
    half8 h, l;
#pragma unroll
    for (int j = 0; j < 8; ++j) {
        _Float16 hv = (_Float16)vs[j];
        h[j] = hv;
        l[j] = (_Float16)(vs[j] - (float)hv);
    }
    size_t o = (size_t)(q * 32 + kt) * 8192 + (size_t)khalf * 2048 + (size_t)code * 8;
    *reinterpret_cast<half8*>(out + o)        = h;
    *reinterpret_cast<half8*>(out + o + 4096) = l;
}

// ---------------------------------------------------------------------------
// One residual-VQ stage (unchanged from round 1, correctness-proven).
// ---------------------------------------------------------------------------
template <bool LAST>
__global__ __launch_bounds__(256, 2)
void vq_stage(int q,
              const float* Rin, float* Rout, const float* zsrc,
              const unsigned short* __restrict__ cbs,
              const float* __restrict__ cb,
              const float* __restrict__ cnorm,
              float* __restrict__ idx_out,
              float* __restrict__ commitP)
{
    __shared__ __align__(16) _Float16 Ab[2][2][2][128][8];
    __shared__ __align__(16) _Float16 Bb[2][2][2][256][8];
    __shared__ float sval[2][128];
    __shared__ int   sidx[2][128];
    __shared__ int   idxbuf[128];
    __shared__ float red[256];

    const int tid  = threadIdx.x;
    const int wid  = tid >> 6;
    const int lane = tid & 63;
    const int l31  = lane & 31;
    const int lh   = lane >> 5;
    const int wm   = wid >> 1;
    const int wn   = wid & 1;
    const int row0 = blockIdx.x * 128;

    f32x16 acc[2][4];
#pragma unroll
    for (int m = 0; m < 2; ++m)
#pragma unroll
        for (int n = 0; n < 4; ++n) acc[m][n] = (f32x16)(0.0f);

    const int arow = tid >> 1;
    const int akh  = tid & 1;

    auto stageB = [&](int db, int kt) {
        const short8* src = reinterpret_cast<const short8*>(cbs + (size_t)(q * 32 + kt) * 8192);
        short8* dst = reinterpret_cast<short8*>(&Bb[db][0][0][0][0]);
#pragma unroll
        for (int i = 0; i < 4; ++i)
            dst[i * 256 + tid] = src[i * 256 + tid];
    };
    auto loadA = [&](int kt, float4& a0, float4& a1) {
        const float* p = Rin + (size_t)(row0 + arow) * HDIM + kt * 16 + akh * 8;
        a0 = *reinterpret_cast<const float4*>(p);
        a1 = *reinterpret_cast<const float4*>(p + 4);
    };
    auto writeA = [&](int db, float4 a0, float4 a1) {
        float vs[8] = {a0.x, a0.y, a0.z, a0.w, a1.x, a1.y, a1.z, a1.w};
        half8 h, l;
#pragma unroll
        for (int j = 0; j < 8; ++j) {
            _Float16 hv = (_Float16)vs[j];
            h[j] = hv;
            l[j] = (_Float16)(vs[j] - (float)hv);
        }
        *reinterpret_cast<half8*>(&Ab[db][0][akh][arow][0]) = h;
        *reinterpret_cast<half8*>(&Ab[db][1][akh][arow][0]) = l;
    };

    {
        float4 ra0, ra1;
        loadA(0, ra0, ra1);
        stageB(0, 0);
        writeA(0, ra0, ra1);
        loadA(1, ra0, ra1);
        stageB(1, 1);
        writeA(1, ra0, ra1);
    }

    float4 pa0, pa1;
    for (int kt = 0; kt < 32; ++kt) {
        const int db = kt & 1;
        __syncthreads();
        if (kt + 2 < 32) loadA(kt + 2, pa0, pa1);

        const int rb = wm * 64 + l31;
        half8 Ah0 = *reinterpret_cast<const half8*>(&Ab[db][0][lh][rb][0]);
        half8 Al0 = *reinterpret_cast<const half8*>(&Ab[db][1][lh][rb][0]);
        half8 Ah1 = *reinterpret_cast<const half8*>(&Ab[db][0][lh][rb + 32][0]);
        half8 Al1 = *reinterpret_cast<const half8*>(&Ab[db][1][lh][rb + 32][0]);
#pragma unroll
        for (int nt = 0; nt < 4; ++nt) {
            const int code = wn * 128 + nt * 32 + l31;
            half8 Bh = *reinterpret_cast<const half8*>(&Bb[db][0][lh][code][0]);
            half8 Bl = *reinterpret_cast<const half8*>(&Bb[db][1][lh][code][0]);
            acc[0][nt] = __builtin_amdgcn_mfma_f32_32x32x16_f16(Ah0, Bh, acc[0][nt], 0, 0, 0);
            acc[0][nt] = __builtin_amdgcn_mfma_f32_32x32x16_f16(Ah0, Bl, acc[0][nt], 0, 0, 0);
            acc[0][nt] = __builtin_amdgcn_mfma_f32_32x32x16_f16(Al0, Bh, acc[0][nt], 0, 0, 0);
            acc[1][nt] = __builtin_amdgcn_mfma_f32_32x32x16_f16(Ah1, Bh, acc[1][nt], 0, 0, 0);
            acc[1][nt] = __builtin_amdgcn_mfma_f32_32x32x16_f16(Ah1, Bl, acc[1][nt], 0, 0, 0);
            acc[1][nt] = __builtin_amdgcn_mfma_f32_32x32x16_f16(Al1, Bh, acc[1][nt], 0, 0, 0);
        }
        __syncthreads();
        if (kt + 2 < 32) { stageB(db, kt + 2); writeA(db, pa0, pa1); }
    }

    const float* cn = cnorm + q * NCODE;
#pragma unroll
    for (int Mt = 0; Mt < 2; ++Mt) {
#pragma unroll
        for (int rg = 0; rg < 16; ++rg) {
            float bv = -FLT_MAX;
            int   bi = 0;
#pragma unroll
            for (int nt = 0; nt < 4; ++nt) {
                const int code = wn * 128 + nt * 32 + l31;
                float s = 2.f * acc[Mt][nt][rg] - cn[code];
                if (s > bv || (s == bv && code < bi)) { bv = s; bi = code; }
            }
#pragma unroll
            for (int m = 1; m < 32; m <<= 1) {
                float ov = __shfl_xor(bv, m, 64);
                int   oi = __shfl_xor(bi, m, 64);
                if (ov > bv || (ov == bv && oi < bi)) { bv = ov; bi = oi; }
            }
            if (l31 == 0) {
                int row = wm * 64 + Mt * 32 + (rg & 3) + 8 * (rg >> 2) + 4 * lh;
                sval[wn][row] = bv;
                sidx[wn][row] = bi;
            }
        }
    }
    __syncthreads();
    if (tid < 128) {
        float v0 = sval[0][tid], v1 = sval[1][tid];
        int   i0 = sidx[0][tid], i1 = sidx[1][tid];
        int b = (v1 > v0 || (v1 == v0 && i1 < i0)) ? i1 : i0;
        idxbuf[tid] = b;
        idx_out[(size_t)(row0 + tid) * NQ + q] = (float)b;
    }
    __syncthreads();

    float ca = 0.f;
    const int rgrp = tid >> 3;
    const int lpos = tid & 7;
#pragma unroll
    for (int rr = 0; rr < 4; ++rr) {
        const int row = rr * 32 + rgrp;
        const float* rin  = Rin + (size_t)(row0 + row) * HDIM;
        const float* crow = cb + ((size_t)q * NCODE + idxbuf[row]) * HDIM;
        float* rout = Rout + (size_t)(row0 + row) * HDIM;
        const float* zr = LAST ? (zsrc + (size_t)(row0 + row) * HDIM) : nullptr;
#pragma unroll
        for (int j = 0; j < 16; ++j) {
            const int f4 = lpos + j * 8;
            float4 rv = *reinterpret_cast<const float4*>(rin + f4 * 4);
            float4 cv = *reinterpret_cast<const float4*>(crow + f4 * 4);
            float4 d;
            d.x = rv.x - cv.x; d.y = rv.y - cv.y;
            d.z = rv.z - cv.z; d.w = rv.w - cv.w;
            ca = fmaf(d.x, d.x, ca); ca = fmaf(d.y, d.y, ca);
            ca = fmaf(d.z, d.z, ca); ca = fmaf(d.w, d.w, ca);
            if constexpr (LAST) {
                float4 zv = *reinterpret_cast<const float4*>(zr + f4 * 4);
                float4 qv;
                qv.x = zv.x - d.x; qv.y = zv.y - d.y;
                qv.z = zv.z - d.z; qv.w = zv.w - d.w;
                *reinterpret_cast<float4*>(rout + f4 * 4) = qv;
            } else {
                *reinterpret_cast<float4*>(rout + f4 * 4) = d;
            }
        }
    }

    red[tid] = ca;
    __syncthreads();
    for (int s = 128; s > 0; s >>= 1) {
        if (tid < s) red[tid] += red[tid + s];
        __syncthreads();
    }
    if (tid == 0) commitP[q * 512 + blockIdx.x] = red[0];
}

// ---------------------------------------------------------------------------
// deterministic final loss reduction
// ---------------------------------------------------------------------------
__global__ __launch_bounds__(256)
void loss_reduce(const float* __restrict__ cP, int nc,
                 const float* __restrict__ rP, int nr,
                 float* __restrict__ out2)
{
    __shared__ float red[256];
    const int tid = threadIdx.x;

    float s = 0.f;
    for (int i = tid; i < nc; i += 256) s += cP[i];
    red[tid] = s;
    __syncthreads();
    for (int st = 128; st > 0; st >>= 1) {
        if (tid < st) red[tid] += red[tid + st];
        __syncthreads();
    }
    float ctot = red[0];
    __syncthreads();

    s = 0.f;
    for (int i = tid; i < nr; i += 256) s += rP[i];
    red[tid] = s;
    __syncthreads();
    for (int st = 128; st > 0; st >>= 1) {
        if (tid < st) red[tid] += red[tid + st];
        __syncthreads();
    }
    if (tid == 0) {
        out2[0] = red[0] / ((float)BATCH * (float)EDIM);
        out2[1] = 0.25f * ctot / ((float)BATCH * (float)HDIM);
    }
}

// ---------------------------------------------------------------------------
extern "C" void kernel_launch(void* const* d_in, const int* in_sizes, int n_in,
                              void* d_out, int out_size, void* d_ws, size_t ws_size,
                              hipStream_t stream)
{
    const float* x   = (const float*)d_in[0];
    const float* ew1 = (const float*)d_in[1];
    const float* eb1 = (const float*)d_in[2];
    const float* ew2 = (const float*)d_in[3];
    const float* eb2 = (const float*)d_in[4];
    const float* cb  = (const float*)d_in[5];
    const float* dw1 = (const float*)d_in[6];
    const float* db1 = (const float*)d_in[7];
    const float* dw2 = (const float*)d_in[8];
    const float* db2 = (const float*)d_in[9];

    float* out  = (float*)d_out;
    float* ws   = (float*)d_ws;
    float* bufA = ws + WS_BUFA;
    float* bufB = ws + WS_BUFB;
    unsigned short* cbs = (unsigned short*)(ws + WS_CBSPL);
    float* cn   = ws + WS_CNORM;
    float* cP   = ws + WS_COMMITP;
    float* rP   = ws + WS_RECONP;
    unsigned short* w1s = (unsigned short*)(ws + WS_W1S);
    unsigned short* w2s = (unsigned short*)(ws + WS_W2S);
    unsigned short* w3s = (unsigned short*)(ws + WS_W3S);
    unsigned short* w4s = (unsigned short*)(ws + WS_W4S);

    // one-shot prep: codebook norms + all f16 hi/lo splits
    cnorm_kernel<<<NQ * NCODE, 64, 0, stream>>>(cb, cn);
    split_cb<<<256, 256, 0, stream>>>(cb, cbs);
    split_w<<<(EDIM / 16) * 2 * HDIM / 256, 256, 0, stream>>>(ew1, w1s, HDIM, EDIM);
    split_w<<<(HDIM / 16) * 2 * HDIM / 256, 256, 0, stream>>>(ew2, w2s, HDIM, HDIM);
    split_w<<<(HDIM / 16) * 2 * HDIM / 256, 256, 0, stream>>>(dw1, w3s, HDIM, HDIM);
    split_w<<<(HDIM / 16) * 2 * EDIM / 256, 256, 0, stream>>>(dw2, w4s, EDIM, HDIM);

    // encoder (MFMA)
    gemm_mfma<256, true, false><<<dim3(HDIM / 256, BATCH / 128), 256, 0, stream>>>(
        x, w1s, eb1, bufA, nullptr, nullptr, HDIM, EDIM);
    gemm_mfma<256, false, false><<<dim3(HDIM / 256, BATCH / 128), 256, 0, stream>>>(
        bufA, w2s, eb2, bufB, nullptr, nullptr, HDIM, HDIM);

    // residual VQ: 4 MFMA stages
    float* idxo = out + OUT_IDX_OFF;
    vq_stage<false><<<512, 256, 0, stream>>>(0, bufB, bufA, nullptr, cbs, cb, cn, idxo, cP);
    vq_stage<false><<<512, 256, 0, stream>>>(1, bufA, bufA, nullptr, cbs, cb, cn, idxo, cP);
    vq_stage<false><<<512, 256, 0, stream>>>(2, bufA, bufA, nullptr, cbs, cb, cn, idxo, cP);
    vq_stage<true ><<<512, 256, 0, stream>>>(3, bufA, bufB, bufB,    cbs, cb, cn, idxo, cP);

    // decoder (MFMA)
    gemm_mfma<256, true, false><<<dim3(HDIM / 256, BATCH / 128), 256, 0, stream>>>(
        bufB, w3s, db1, bufA, nullptr, nullptr, HDIM, HDIM);
    gemm_mfma<128, false, true><<<dim3(EDIM / 128, BATCH / 128), 256, 0, stream>>>(
        bufA, w4s, db2, out, x, rP, EDIM, HDIM);

    // losses
    loss_reduce<<<1, 256, 0, stream>>>(cP, NQ * 512, rP,
                                       (BATCH / 128) * (EDIM / 128),
                                       out + OUT_RL_OFF);
}